// Round 4
// baseline (159.251 us; speedup 1.0000x reference)
//
#include <hip/hip_runtime.h>

// Problem constants (B=4, S=2048, H=1024, E=8)
#define H 1024
#define E 8
#define T 8192          // B*S
#define CAP 1024        // T/E, capacity_factor=1.0 top-1

typedef __bf16 bf16x8 __attribute__((ext_vector_type(8)));
typedef float  f32x4  __attribute__((ext_vector_type(4)));
typedef unsigned short u16;

// round-to-nearest-even f32 -> bf16 bits
__device__ __forceinline__ u16 f2bf(float f) {
    union { float f; unsigned u; } v; v.f = f;
    unsigned r = v.u + 0x7FFFu + ((v.u >> 16) & 1u);
    return (u16)(r >> 16);
}

// async global->LDS, 16 B per lane
typedef __attribute__((address_space(1))) const void* gas_t;
typedef __attribute__((address_space(3))) void* las_t;
__device__ __forceinline__ void gld16(const void* g, void* l) {
    __builtin_amdgcn_global_load_lds((gas_t)g, (las_t)l, 16, 0, 0);
}

// ---------------------------------------------------------------------------
// Kernel 0: wg [H][E] -> wgT [E][H] (fp32). One thread per h: coalesced
// float4x2 row read, 8 coalesced scalar writes (stride-4B across lanes).
// ---------------------------------------------------------------------------
__global__ __launch_bounds__(256) void wgt_kernel(
    const float* __restrict__ wg, float* __restrict__ wgT) {
    const int h = blockIdx.x * 256 + threadIdx.x;
    float4 lo = *(const float4*)(wg + h * E);
    float4 hi = *(const float4*)(wg + h * E + 4);
    wgT[0 * H + h] = lo.x; wgT[1 * H + h] = lo.y;
    wgT[2 * H + h] = lo.z; wgT[3 * H + h] = lo.w;
    wgT[4 * H + h] = hi.x; wgT[5 * H + h] = hi.y;
    wgT[6 * H + h] = hi.z; wgT[7 * H + h] = hi.w;
}

// ---------------------------------------------------------------------------
// Kernel 1: fused gate + x->bf16 + W->bf16. NO LDS (occupancy-limited only
// by VGPRs). Blocks [0,512): gating, 16 tok/block (4/wave); wgT float4 reads
// are fully coalesced and L1/L2-resident. Blocks [512,2048): W fp32->bf16.
// ---------------------------------------------------------------------------
#define GATE_BLOCKS 512
#define CVT_BLOCKS  1536

__global__ __launch_bounds__(256) void gatecvt_kernel(
    const float* __restrict__ x, const float* __restrict__ wgT,
    const float* __restrict__ W,
    int* __restrict__ eid, float* __restrict__ gate,
    u16* __restrict__ xbf, u16* __restrict__ Wbf) {
    const int tid = threadIdx.x;

    if (blockIdx.x >= GATE_BLOCKS) {       // ---- W conversion ----
        int i = (blockIdx.x - GATE_BLOCKS) * 256 + tid;
        const int n4 = E * H * H / 4;
        const int stride = CVT_BLOCKS * 256;
        for (; i < n4; i += stride) {
            float4 v = ((const float4*)W)[i];
            ushort4 o;
            o.x = f2bf(v.x); o.y = f2bf(v.y); o.z = f2bf(v.z); o.w = f2bf(v.w);
            ((ushort4*)Wbf)[i] = o;
        }
        return;
    }

    // ---- gating ----
    const int wv = tid >> 6, lane = tid & 63;
    const int tbase = blockIdx.x * 16 + wv * 4;
    const int h00 = lane * 4;

    float a[4][8];
    #pragma unroll
    for (int j = 0; j < 4; ++j)
        #pragma unroll
        for (int e = 0; e < 8; ++e) a[j][e] = 0.f;

    #pragma unroll
    for (int q = 0; q < 4; ++q) {
        const int h0 = q * 256 + h00;
        float4 xv[4];
        #pragma unroll
        for (int j = 0; j < 4; ++j)
            xv[j] = *(const float4*)(x + (size_t)(tbase + j) * H + h0);
        #pragma unroll
        for (int j = 0; j < 4; ++j) {
            ushort4 o;
            o.x = f2bf(xv[j].x); o.y = f2bf(xv[j].y);
            o.z = f2bf(xv[j].z); o.w = f2bf(xv[j].w);
            *(ushort4*)(xbf + (size_t)(tbase + j) * H + h0) = o;
        }
        #pragma unroll
        for (int e = 0; e < 8; ++e) {
            const float4 w4 = *(const float4*)(wgT + e * H + h0);
            #pragma unroll
            for (int j = 0; j < 4; ++j)
                a[j][e] += xv[j].x * w4.x + xv[j].y * w4.y
                         + xv[j].z * w4.z + xv[j].w * w4.w;
        }
    }

    const bool b0 = lane & 1, b1 = lane & 2, b2 = lane & 4;
    const int elane = ((lane & 1) << 2) | (lane & 2) | ((lane >> 2) & 1);

    #pragma unroll
    for (int j = 0; j < 4; ++j) {
        float* A = a[j];
        #pragma unroll
        for (int k = 0; k < 4; ++k) {     // fold 8 -> 4 (xor 1)
            float t = b0 ? A[k] : A[k + 4];
            t = __shfl_xor(t, 1);
            A[k] = (b0 ? A[k + 4] : A[k]) + t;
        }
        #pragma unroll
        for (int k = 0; k < 2; ++k) {     // fold 4 -> 2 (xor 2)
            float t = b1 ? A[k] : A[k + 2];
            t = __shfl_xor(t, 2);
            A[k] = (b1 ? A[k + 2] : A[k]) + t;
        }
        {                                  // fold 2 -> 1 (xor 4)
            float t = b2 ? A[0] : A[1];
            t = __shfl_xor(t, 4);
            A[0] = (b2 ? A[1] : A[0]) + t;
        }
        float v = A[0];
        v += __shfl_xor(v, 8); v += __shfl_xor(v, 16); v += __shfl_xor(v, 32);
        float m = v; int mi = elane;
        #pragma unroll
        for (int off = 1; off <= 4; off <<= 1) {
            float om = __shfl_xor(m, off);
            int   oi = __shfl_xor(mi, off);
            if (om > m || (om == m && oi < mi)) { m = om; mi = oi; }
        }
        float s = expf(v - m);
        s += __shfl_xor(s, 1); s += __shfl_xor(s, 2); s += __shfl_xor(s, 4);
        if (lane == 0) {
            eid[tbase + j]  = mi;
            gate[tbase + j] = 1.0f / s;
        }
    }
}

// ---------------------------------------------------------------------------
// Kernel 2: capacity scan (single block), hierarchical LDS prefix.
// ---------------------------------------------------------------------------
#define TPT 32
__global__ __launch_bounds__(256) void scan_kernel(
    const int* __restrict__ eid, float* __restrict__ gate,
    int* __restrict__ perm) {
    __shared__ int cnt[256][E];
    __shared__ int base[256][E];
    __shared__ int part[E][8];
    const int tid = threadIdx.x;

    for (int i = tid; i < E * CAP; i += 256) perm[i] = -1;

    const int t0 = tid * TPT;
    int c[E];
    #pragma unroll
    for (int e = 0; e < E; ++e) c[e] = 0;
    for (int i = 0; i < TPT; ++i) {
        const int ei = eid[t0 + i];
        #pragma unroll
        for (int e = 0; e < E; ++e) c[e] += (ei == e);
    }
    #pragma unroll
    for (int e = 0; e < E; ++e) cnt[tid][e] = c[e];
    __syncthreads();
    if (tid < 64) {
        const int e = tid >> 3, j = tid & 7;
        int s = 0;
        for (int i = j * 32; i < j * 32 + 32; ++i) s += cnt[i][e];
        part[e][j] = s;
    }
    __syncthreads();
    if (tid < E) {
        int run = 0;
        #pragma unroll
        for (int j = 0; j < 8; ++j) { int v = part[tid][j]; part[tid][j] = run; run += v; }
    }
    __syncthreads();
    if (tid < 64) {
        const int e = tid >> 3, j = tid & 7;
        int run = part[e][j];
        for (int i = j * 32; i < j * 32 + 32; ++i) { base[i][e] = run; run += cnt[i][e]; }
    }
    __syncthreads();
    #pragma unroll
    for (int e = 0; e < E; ++e) c[e] = base[tid][e];
    for (int i = 0; i < TPT; ++i) {
        const int t = t0 + i;
        const int ei = eid[t];
        int pos = 0;
        #pragma unroll
        for (int e = 0; e < E; ++e) if (ei == e) pos = c[e]++;
        if (pos < CAP) perm[ei * CAP + pos] = t;
        else gate[t] = 0.f;               // dropped; kept tokens have gate >= 1/8
    }
}

// ---------------------------------------------------------------------------
// Kernel 3: bf16 gathered GEMM. Tile 128x128, K-step 128 per barrier pair
// (two 128x64 half-buffers filled in one staging burst: 16 gld16/thread,
// 64 MFMA/wave between barriers). XOR-swizzled LDS. Grid (8, 8, 9):
// z in [0,8) = experts; z == 8 = zero-dropped-rows plane.
// ---------------------------------------------------------------------------
__global__ __launch_bounds__(256) void moe_gemm_bf(
    const u16* __restrict__ xbf, const u16* __restrict__ Wbf,
    const float* __restrict__ bias, const int* __restrict__ perm,
    const float* __restrict__ gate, float* __restrict__ out) {
    __shared__ __align__(16) u16 As[2][128 * 64];   // 32 KB
    __shared__ __align__(16) u16 Bs[2][128 * 64];   // 32 KB
    __shared__ int   perm_s[128];
    __shared__ float gate_s[128];

    const int tid = threadIdx.x;

    if (blockIdx.z == 8) {          // ---- zero rows of dropped tokens ----
        const int t = (blockIdx.y * 8 + blockIdx.x) * 128 + (tid >> 1);
        if (gate[t] == 0.f) {
            const int half = tid & 1;
            float4 z = make_float4(0.f, 0.f, 0.f, 0.f);
            float4* o = (float4*)(out + (size_t)t * H + half * 512);
            #pragma unroll
            for (int i = 0; i < 128; ++i) o[i] = z;
        }
        return;
    }

    const int e  = blockIdx.z;
    const int mb = blockIdx.y;
    const int fb = blockIdx.x;

    if (tid < 128) {
        const int t = perm[e * CAP + mb * 128 + tid];
        perm_s[tid] = t;
        gate_s[tid] = (t >= 0) ? gate[t] : 0.f;
    }
    __syncthreads();

    const int lane = tid & 63;
    const int wv = tid >> 6;
    const int wm = wv >> 1, wn = wv & 1;
    const int l16 = lane & 15, quad = lane >> 4;

    const int rl  = lane >> 3;           // row within the 8-row group
    const int cch = lane & 7;            // LDS 16B-chunk slot
    const int gch = cch ^ rl;            // swizzled global chunk
    const u16* ga[4]; const u16* gb[4];
    #pragma unroll
    for (int q = 0; q < 4; ++q) {
        const int r = (wv * 4 + q) * 8 + rl;
        const int tA = perm_s[r];
        const int tok = tA >= 0 ? tA : 0;
        ga[q] = xbf + (size_t)tok * H + gch * 8;
        gb[q] = Wbf + (size_t)e * H * H + (size_t)(fb * 128 + r) * H + gch * 8;
    }

    f32x4 acc[4][4] = {};

    for (int kt = 0; kt < H / 128; ++kt) {
        __syncthreads();
        #pragma unroll
        for (int hb = 0; hb < 2; ++hb)
            #pragma unroll
            for (int q = 0; q < 4; ++q) {
                gld16(ga[q] + hb * 64, &As[hb][(wv * 4 + q) * 512 + lane * 8]);
                gld16(gb[q] + hb * 64, &Bs[hb][(wv * 4 + q) * 512 + lane * 8]);
            }
        #pragma unroll
        for (int q = 0; q < 4; ++q) { ga[q] += 128; gb[q] += 128; }
        __syncthreads();
        #pragma unroll
        for (int hb = 0; hb < 2; ++hb)
            #pragma unroll
            for (int s = 0; s < 2; ++s) {
                bf16x8 af[4], bfr[4];
                const int cc = (s * 4 + quad) ^ (l16 & 7);
                #pragma unroll
                for (int i = 0; i < 4; ++i) {
                    af[i]  = *(const bf16x8*)&As[hb][(wm * 64 + i * 16 + l16) * 64 + cc * 8];
                    bfr[i] = *(const bf16x8*)&Bs[hb][(wn * 64 + i * 16 + l16) * 64 + cc * 8];
                }
                #pragma unroll
                for (int mi = 0; mi < 4; ++mi)
                    #pragma unroll
                    for (int ni = 0; ni < 4; ++ni)
                        acc[mi][ni] = __builtin_amdgcn_mfma_f32_16x16x32_bf16(
                            af[mi], bfr[ni], acc[mi][ni], 0, 0, 0);
            }
    }

    // epilogue: C/D layout col=lane&15, row=quad*4+reg
    float bv[4];
    #pragma unroll
    for (int ni = 0; ni < 4; ++ni)
        bv[ni] = bias[e * H + fb * 128 + wn * 64 + ni * 16 + l16];

    #pragma unroll
    for (int mi = 0; mi < 4; ++mi) {
        #pragma unroll
        for (int r = 0; r < 4; ++r) {
            const int rowl = wm * 64 + mi * 16 + quad * 4 + r;
            const int t = perm_s[rowl];
            if (t < 0) continue;
            const float g = gate_s[rowl];
            float* orow = out + (size_t)t * H + fb * 128 + wn * 64;
            #pragma unroll
            for (int ni = 0; ni < 4; ++ni)
                orow[ni * 16 + l16] = g * (acc[mi][ni][r] + bv[ni]);
        }
    }
}

extern "C" void kernel_launch(void* const* d_in, const int* in_sizes, int n_in,
                              void* d_out, int out_size, void* d_ws, size_t ws_size,
                              hipStream_t stream) {
    const float* x    = (const float*)d_in[0];  // [T,H]
    const float* wg   = (const float*)d_in[1];  // [H,E]
    const float* W    = (const float*)d_in[2];  // [E,H,H]
    const float* bias = (const float*)d_in[3];  // [E,H]
    float* out = (float*)d_out;

    // ws: eid[T] | gate[T] | perm[E*CAP] | wgT[E*H] f32 | xbf[T*H] bf16 | Wbf
    int*   eid  = (int*)d_ws;
    float* gate = (float*)((char*)d_ws + (size_t)T * 4);
    int*   perm = (int*)((char*)d_ws + (size_t)T * 8);
    float* wgT  = (float*)((char*)d_ws + (size_t)T * 12);
    u16*   xbf  = (u16*)((char*)d_ws + (size_t)T * 12 + (size_t)E * H * 4);
    u16*   Wbf  = xbf + (size_t)T * H;

    wgt_kernel<<<H / 256, 256, 0, stream>>>(wg, wgT);
    gatecvt_kernel<<<GATE_BLOCKS + CVT_BLOCKS, 256, 0, stream>>>(
        x, wgT, W, eid, gate, xbf, Wbf);
    scan_kernel<<<1, 256, 0, stream>>>(eid, gate, perm);
    moe_gemm_bf<<<dim3(8, 8, 9), 256, 0, stream>>>(xbf, Wbf, bias, perm, gate, out);
}

// Round 5
// 153.375 us; speedup vs baseline: 1.0383x; 1.0383x over previous
//
#include <hip/hip_runtime.h>

// Problem constants (B=4, S=2048, H=1024, E=8)
#define H 1024
#define E 8
#define T 8192          // B*S
#define CAP 1024        // T/E, capacity_factor=1.0 top-1

typedef __bf16 bf16x8 __attribute__((ext_vector_type(8)));
typedef float  f32x4  __attribute__((ext_vector_type(4)));
typedef unsigned short u16;

// round-to-nearest-even f32 -> bf16 bits
__device__ __forceinline__ u16 f2bf(float f) {
    union { float f; unsigned u; } v; v.f = f;
    unsigned r = v.u + 0x7FFFu + ((v.u >> 16) & 1u);
    return (u16)(r >> 16);
}

// async global->LDS, 16 B per lane
typedef __attribute__((address_space(1))) const void* gas_t;
typedef __attribute__((address_space(3))) void* las_t;
__device__ __forceinline__ void gld16(const void* g, void* l) {
    __builtin_amdgcn_global_load_lds((gas_t)g, (las_t)l, 16, 0, 0);
}

// ---------------------------------------------------------------------------
// Kernel 0: wg [H][E] -> wgT [E][H] (fp32)
// ---------------------------------------------------------------------------
__global__ __launch_bounds__(256) void wgt_kernel(
    const float* __restrict__ wg, float* __restrict__ wgT) {
    const int h = blockIdx.x * 256 + threadIdx.x;
    float4 lo = *(const float4*)(wg + h * E);
    float4 hi = *(const float4*)(wg + h * E + 4);
    wgT[0 * H + h] = lo.x; wgT[1 * H + h] = lo.y;
    wgT[2 * H + h] = lo.z; wgT[3 * H + h] = lo.w;
    wgT[4 * H + h] = hi.x; wgT[5 * H + h] = hi.y;
    wgT[6 * H + h] = hi.z; wgT[7 * H + h] = hi.w;
}

// ---------------------------------------------------------------------------
// Kernel 1: fused gate + x->bf16 + W->bf16 (no LDS). Blocks [0,512): gating,
// 16 tok/block (4/wave). Blocks [512,2048): W fp32->bf16 grid-stride.
// ---------------------------------------------------------------------------
#define GATE_BLOCKS 512
#define CVT_BLOCKS  1536

__global__ __launch_bounds__(256) void gatecvt_kernel(
    const float* __restrict__ x, const float* __restrict__ wgT,
    const float* __restrict__ W,
    int* __restrict__ eid, float* __restrict__ gate,
    u16* __restrict__ xbf, u16* __restrict__ Wbf) {
    const int tid = threadIdx.x;

    if (blockIdx.x >= GATE_BLOCKS) {       // ---- W conversion ----
        int i = (blockIdx.x - GATE_BLOCKS) * 256 + tid;
        const int n4 = E * H * H / 4;
        const int stride = CVT_BLOCKS * 256;
        for (; i < n4; i += stride) {
            float4 v = ((const float4*)W)[i];
            ushort4 o;
            o.x = f2bf(v.x); o.y = f2bf(v.y); o.z = f2bf(v.z); o.w = f2bf(v.w);
            ((ushort4*)Wbf)[i] = o;
        }
        return;
    }

    // ---- gating ----
    const int wv = tid >> 6, lane = tid & 63;
    const int tbase = blockIdx.x * 16 + wv * 4;
    const int h00 = lane * 4;

    float a[4][8];
    #pragma unroll
    for (int j = 0; j < 4; ++j)
        #pragma unroll
        for (int e = 0; e < 8; ++e) a[j][e] = 0.f;

    #pragma unroll
    for (int q = 0; q < 4; ++q) {
        const int h0 = q * 256 + h00;
        float4 xv[4];
        #pragma unroll
        for (int j = 0; j < 4; ++j)
            xv[j] = *(const float4*)(x + (size_t)(tbase + j) * H + h0);
        #pragma unroll
        for (int j = 0; j < 4; ++j) {
            ushort4 o;
            o.x = f2bf(xv[j].x); o.y = f2bf(xv[j].y);
            o.z = f2bf(xv[j].z); o.w = f2bf(xv[j].w);
            *(ushort4*)(xbf + (size_t)(tbase + j) * H + h0) = o;
        }
        #pragma unroll
        for (int e = 0; e < 8; ++e) {
            const float4 w4 = *(const float4*)(wgT + e * H + h0);
            #pragma unroll
            for (int j = 0; j < 4; ++j)
                a[j][e] += xv[j].x * w4.x + xv[j].y * w4.y
                         + xv[j].z * w4.z + xv[j].w * w4.w;
        }
    }

    const bool b0 = lane & 1, b1 = lane & 2, b2 = lane & 4;
    const int elane = ((lane & 1) << 2) | (lane & 2) | ((lane >> 2) & 1);

    #pragma unroll
    for (int j = 0; j < 4; ++j) {
        float* A = a[j];
        #pragma unroll
        for (int k = 0; k < 4; ++k) {
            float t = b0 ? A[k] : A[k + 4];
            t = __shfl_xor(t, 1);
            A[k] = (b0 ? A[k + 4] : A[k]) + t;
        }
        #pragma unroll
        for (int k = 0; k < 2; ++k) {
            float t = b1 ? A[k] : A[k + 2];
            t = __shfl_xor(t, 2);
            A[k] = (b1 ? A[k + 2] : A[k]) + t;
        }
        {
            float t = b2 ? A[0] : A[1];
            t = __shfl_xor(t, 4);
            A[0] = (b2 ? A[1] : A[0]) + t;
        }
        float v = A[0];
        v += __shfl_xor(v, 8); v += __shfl_xor(v, 16); v += __shfl_xor(v, 32);
        float m = v; int mi = elane;
        #pragma unroll
        for (int off = 1; off <= 4; off <<= 1) {
            float om = __shfl_xor(m, off);
            int   oi = __shfl_xor(mi, off);
            if (om > m || (om == m && oi < mi)) { m = om; mi = oi; }
        }
        float s = expf(v - m);
        s += __shfl_xor(s, 1); s += __shfl_xor(s, 2); s += __shfl_xor(s, 4);
        if (lane == 0) {
            eid[tbase + j]  = mi;
            gate[tbase + j] = 1.0f / s;
        }
    }
}

// ---------------------------------------------------------------------------
// Kernel 2: capacity scan (single block), hierarchical LDS prefix.
// ---------------------------------------------------------------------------
#define TPT 32
__global__ __launch_bounds__(256) void scan_kernel(
    const int* __restrict__ eid, float* __restrict__ gate,
    int* __restrict__ perm) {
    __shared__ int cnt[256][E];
    __shared__ int base[256][E];
    __shared__ int part[E][8];
    const int tid = threadIdx.x;

    for (int i = tid; i < E * CAP; i += 256) perm[i] = -1;

    const int t0 = tid * TPT;
    int c[E];
    #pragma unroll
    for (int e = 0; e < E; ++e) c[e] = 0;
    for (int i = 0; i < TPT; ++i) {
        const int ei = eid[t0 + i];
        #pragma unroll
        for (int e = 0; e < E; ++e) c[e] += (ei == e);
    }
    #pragma unroll
    for (int e = 0; e < E; ++e) cnt[tid][e] = c[e];
    __syncthreads();
    if (tid < 64) {
        const int e = tid >> 3, j = tid & 7;
        int s = 0;
        for (int i = j * 32; i < j * 32 + 32; ++i) s += cnt[i][e];
        part[e][j] = s;
    }
    __syncthreads();
    if (tid < E) {
        int run = 0;
        #pragma unroll
        for (int j = 0; j < 8; ++j) { int v = part[tid][j]; part[tid][j] = run; run += v; }
    }
    __syncthreads();
    if (tid < 64) {
        const int e = tid >> 3, j = tid & 7;
        int run = part[e][j];
        for (int i = j * 32; i < j * 32 + 32; ++i) { base[i][e] = run; run += cnt[i][e]; }
    }
    __syncthreads();
    #pragma unroll
    for (int e = 0; e < E; ++e) c[e] = base[tid][e];
    for (int i = 0; i < TPT; ++i) {
        const int t = t0 + i;
        const int ei = eid[t];
        int pos = 0;
        #pragma unroll
        for (int e = 0; e < E; ++e) if (ei == e) pos = c[e]++;
        if (pos < CAP) perm[ei * CAP + pos] = t;
        else gate[t] = 0.f;               // dropped; kept tokens have gate >= 1/8
    }
}

// ---------------------------------------------------------------------------
// Kernel 3: bf16 gathered GEMM, 512 threads (8 waves as 2x4: 64x32/wave).
// Tile 128x128, BK=128 (two 128x64 halves). XOR-swizzled LDS,
// global_load_lds width-16. 1-D grid, XCD swizzle: e = idx&7 so each
// expert's 64 blocks share one XCD's L2 (W_e 2MB + x_e 2MB ~ 4MB L2).
// idx >= 512: zero-dropped-rows plane.
// ---------------------------------------------------------------------------
__global__ __launch_bounds__(512, 4) void moe_gemm_bf(
    const u16* __restrict__ xbf, const u16* __restrict__ Wbf,
    const float* __restrict__ bias, const int* __restrict__ perm,
    const float* __restrict__ gate, float* __restrict__ out) {
    __shared__ __align__(16) u16 As[2][128 * 64];   // 32 KB
    __shared__ __align__(16) u16 Bs[2][128 * 64];   // 32 KB
    __shared__ int   perm_s[128];
    __shared__ float gate_s[128];

    const int tid = threadIdx.x;
    const int idx = blockIdx.x;

    if (idx >= 512) {               // ---- zero rows of dropped tokens ----
        const int t = (idx - 512) * 128 + (tid >> 2);
        if (gate[t] == 0.f) {
            const int part = tid & 3;
            float4 z = make_float4(0.f, 0.f, 0.f, 0.f);
            float4* o = (float4*)(out + (size_t)t * H + part * 256);
            #pragma unroll
            for (int i = 0; i < 64; ++i) o[i] = z;
        }
        return;
    }

    const int fb = idx >> 6;          // feature block
    const int mb = (idx >> 3) & 7;    // slot block
    const int e  = idx & 7;           // expert -> XCD (round-robin heuristic)

    if (tid < 128) {
        const int t = perm[e * CAP + mb * 128 + tid];
        perm_s[tid] = t;
        gate_s[tid] = (t >= 0) ? gate[t] : 0.f;
    }
    __syncthreads();

    const int lane = tid & 63;
    const int wv = tid >> 6;          // 0..7
    const int wm = wv >> 2;           // 0..1 : 64-row half
    const int wn = wv & 3;            // 0..3 : 32-col quarter
    const int l16 = lane & 15, quad = lane >> 4;

    // staging: per half-buffer, wave wv covers rows [wv*16, wv*16+16)
    // (2 instrs of 8 rows); chunk slot = lane&7, global chunk = slot ^ (row&7)
    const int rl  = lane >> 3;        // row within 8-row group
    const int cch = lane & 7;
    const int gch = cch ^ rl;
    const u16* ga[2]; const u16* gb[2];
    #pragma unroll
    for (int q = 0; q < 2; ++q) {
        const int r = wv * 16 + q * 8 + rl;
        const int tA = perm_s[r];
        const int tok = tA >= 0 ? tA : 0;
        ga[q] = xbf + (size_t)tok * H + gch * 8;
        gb[q] = Wbf + (size_t)e * H * H + (size_t)(fb * 128 + r) * H + gch * 8;
    }

    f32x4 acc[4][2] = {};

    for (int kt = 0; kt < H / 128; ++kt) {
        __syncthreads();
        #pragma unroll
        for (int hb = 0; hb < 2; ++hb)
            #pragma unroll
            for (int q = 0; q < 2; ++q) {
                u16* la = &As[hb][(wv * 16 + q * 8) * 64 + lane * 8];
                u16* lb = &Bs[hb][(wv * 16 + q * 8) * 64 + lane * 8];
                gld16(ga[q] + hb * 64, la);
                gld16(gb[q] + hb * 64, lb);
            }
        #pragma unroll
        for (int q = 0; q < 2; ++q) { ga[q] += 128; gb[q] += 128; }
        __syncthreads();
        #pragma unroll
        for (int hb = 0; hb < 2; ++hb)
            #pragma unroll
            for (int s = 0; s < 2; ++s) {
                bf16x8 af[4], bfr[2];
                const int cc = (s * 4 + quad) ^ (l16 & 7);
                #pragma unroll
                for (int i = 0; i < 4; ++i)
                    af[i] = *(const bf16x8*)&As[hb][(wm * 64 + i * 16 + l16) * 64 + cc * 8];
                #pragma unroll
                for (int i = 0; i < 2; ++i)
                    bfr[i] = *(const bf16x8*)&Bs[hb][(wn * 32 + i * 16 + l16) * 64 + cc * 8];
                #pragma unroll
                for (int mi = 0; mi < 4; ++mi)
                    #pragma unroll
                    for (int ni = 0; ni < 2; ++ni)
                        acc[mi][ni] = __builtin_amdgcn_mfma_f32_16x16x32_bf16(
                            af[mi], bfr[ni], acc[mi][ni], 0, 0, 0);
            }
    }

    // epilogue: C/D layout col=lane&15, row=quad*4+reg
    float bv[2];
    #pragma unroll
    for (int ni = 0; ni < 2; ++ni)
        bv[ni] = bias[e * H + fb * 128 + wn * 32 + ni * 16 + l16];

    #pragma unroll
    for (int mi = 0; mi < 4; ++mi) {
        #pragma unroll
        for (int r = 0; r < 4; ++r) {
            const int rowl = wm * 64 + mi * 16 + quad * 4 + r;
            const int t = perm_s[rowl];
            if (t < 0) continue;
            const float g = gate_s[rowl];
            float* orow = out + (size_t)t * H + fb * 128 + wn * 32;
            #pragma unroll
            for (int ni = 0; ni < 2; ++ni)
                orow[ni * 16 + l16] = g * (acc[mi][ni][r] + bv[ni]);
        }
    }
}

extern "C" void kernel_launch(void* const* d_in, const int* in_sizes, int n_in,
                              void* d_out, int out_size, void* d_ws, size_t ws_size,
                              hipStream_t stream) {
    const float* x    = (const float*)d_in[0];  // [T,H]
    const float* wg   = (const float*)d_in[1];  // [H,E]
    const float* W    = (const float*)d_in[2];  // [E,H,H]
    const float* bias = (const float*)d_in[3];  // [E,H]
    float* out = (float*)d_out;

    // ws: eid[T] | gate[T] | perm[E*CAP] | wgT[E*H] f32 | xbf[T*H] bf16 | Wbf
    int*   eid  = (int*)d_ws;
    float* gate = (float*)((char*)d_ws + (size_t)T * 4);
    int*   perm = (int*)((char*)d_ws + (size_t)T * 8);
    float* wgT  = (float*)((char*)d_ws + (size_t)T * 12);
    u16*   xbf  = (u16*)((char*)d_ws + (size_t)T * 12 + (size_t)E * H * 4);
    u16*   Wbf  = xbf + (size_t)T * H;

    wgt_kernel<<<H / 256, 256, 0, stream>>>(wg, wgT);
    gatecvt_kernel<<<GATE_BLOCKS + CVT_BLOCKS, 256, 0, stream>>>(
        x, wgT, W, eid, gate, xbf, Wbf);
    scan_kernel<<<1, 256, 0, stream>>>(eid, gate, perm);
    moe_gemm_bf<<<512 + 64, 512, 0, stream>>>(xbf, Wbf, bias, perm, gate, out);
}